// Round 1
// baseline (246.590 us; speedup 1.0000x reference)
//
#include <hip/hip_runtime.h>
#include <hip/hip_bf16.h>
#include <math.h>

#define EMBED 1024
#define NHEAD 16
#define HD 64
#define BATCH 2
#define SEQ 2048
#define MTOT (BATCH * SEQ)   // 4096
#define QKVN (3 * EMBED)     // 3072

typedef __attribute__((ext_vector_type(8))) short short8;
typedef __attribute__((ext_vector_type(4))) float f32x4;

__device__ __forceinline__ unsigned short f2bf(float f) {
  unsigned u = __builtin_bit_cast(unsigned, f);
  u += 0x7fffu + ((u >> 16) & 1u);   // RNE
  return (unsigned short)(u >> 16);
}

// ---------------- prep kernels ----------------

__global__ __launch_bounds__(256) void k_cvt(const float* __restrict__ in,
                                             unsigned short* __restrict__ out, int n4) {
  int i = blockIdx.x * 256 + threadIdx.x;
  if (i >= n4) return;
  float4 v = reinterpret_cast<const float4*>(in)[i];
  ushort4 o;
  o.x = f2bf(v.x); o.y = f2bf(v.y); o.z = f2bf(v.z); o.w = f2bf(v.w);
  reinterpret_cast<ushort4*>(out)[i] = o;
}

// W [K][Ncols] f32 -> WT [Ncols][K] bf16
__global__ __launch_bounds__(256) void k_transpose_cvt(const float* __restrict__ W,
                                                       unsigned short* __restrict__ WT,
                                                       int K, int Ncols) {
  __shared__ float tile[32][33];
  int n0 = blockIdx.x * 32, k0 = blockIdx.y * 32;
  int tc = threadIdx.x & 31, tr = threadIdx.x >> 5;
  for (int i = 0; i < 4; i++) {
    int r = tr + i * 8;
    tile[r][tc] = W[(size_t)(k0 + r) * Ncols + n0 + tc];
  }
  __syncthreads();
  for (int i = 0; i < 4; i++) {
    int r = tr + i * 8;
    WT[(size_t)(n0 + r) * K + k0 + tc] = f2bf(tile[tc][r]);
  }
}

__global__ __launch_bounds__(256) void k_rope_tables(float* __restrict__ cosT,
                                                     float* __restrict__ sinT) {
  int idx = blockIdx.x * 256 + threadIdx.x;
  if (idx >= SEQ * 32) return;
  int pos = idx >> 5, i = idx & 31;
  double theta = exp((double)i * -0.28782313662425575);  // ln(10000)/32
  double f = (double)pos * theta;
  cosT[idx] = (float)cos(f);
  sinT[idx] = (float)sin(f);
}

// ---------------- shared GEMM mainloop ----------------
// C tile 128x128, BK=64, 4 waves (2x2), wave tile 64x64 = 4x4 frags of 16x16.
// A: [M][1024] bf16 row-major.  Bt: [N][1024] bf16 (B transposed).
__device__ __forceinline__ void gemm_mainloop(const unsigned short* __restrict__ A,
                                              const unsigned short* __restrict__ Bt,
                                              unsigned short* Al, unsigned short* Bl,
                                              size_t m0, size_t n0,
                                              int tid, int l15, int g, int wm, int wn,
                                              f32x4 acc[4][4]) {
  for (int k0 = 0; k0 < 1024; k0 += 64) {
    __syncthreads();
    for (int it = 0; it < 4; it++) {
      int idx = it * 256 + tid;
      int row = idx >> 3, ch = idx & 7;
      uint4 va = *reinterpret_cast<const uint4*>(A + (m0 + row) * 1024 + k0 + ch * 8);
      *reinterpret_cast<uint4*>(Al + row * 72 + ch * 8) = va;
      uint4 vb = *reinterpret_cast<const uint4*>(Bt + (n0 + row) * 1024 + k0 + ch * 8);
      *reinterpret_cast<uint4*>(Bl + row * 72 + ch * 8) = vb;
    }
    __syncthreads();
    for (int kk = 0; kk < 2; kk++) {
      short8 fa[4], fb[4];
      for (int i = 0; i < 4; i++)
        fa[i] = *reinterpret_cast<const short8*>(Al + (wm * 64 + i * 16 + l15) * 72 + kk * 32 + g * 8);
      for (int j = 0; j < 4; j++)
        fb[j] = *reinterpret_cast<const short8*>(Bl + (wn * 64 + j * 16 + l15) * 72 + kk * 32 + g * 8);
      for (int i = 0; i < 4; i++)
        for (int j = 0; j < 4; j++)
          acc[i][j] = __builtin_amdgcn_mfma_f32_16x16x32_bf16(fa[i], fb[j], acc[i][j], 0, 0, 0);
    }
  }
}

// ---------------- QKV GEMM + bias + RoPE + scatter ----------------
__global__ __launch_bounds__(256) void k_qkv_gemm(const unsigned short* __restrict__ A,
                                                  const unsigned short* __restrict__ Bt,
                                                  const float* __restrict__ bias,
                                                  const float* __restrict__ cosT,
                                                  const float* __restrict__ sinT,
                                                  unsigned short* __restrict__ Qb,
                                                  unsigned short* __restrict__ Kb,
                                                  unsigned short* __restrict__ Vb) {
  __shared__ alignas(16) unsigned short Al[128 * 72];
  __shared__ alignas(16) unsigned short Bl[128 * 72];
  const int tid = threadIdx.x;
  const int lane = tid & 63, l15 = lane & 15, g = lane >> 4;
  const int wid = tid >> 6, wm = wid >> 1, wn = wid & 1;
  const size_t m0 = (size_t)blockIdx.y * 128;
  const size_t n0 = (size_t)blockIdx.x * 128;
  f32x4 acc[4][4] = {};
  gemm_mainloop(A, Bt, Al, Bl, m0, n0, tid, l15, g, wm, wn, acc);

  const int cbase = (int)n0 + wn * 64;       // wave spans exactly one head (64 cols)
  const int sec = cbase >> 10;               // 0=Q 1=K 2=V
  const int head = (cbase & 1023) >> 6;
  float bia[4];
  for (int j = 0; j < 4; j++) bia[j] = bias[cbase + j * 16 + l15];
  const size_t mw = m0 + wm * 64;

  if (sec == 2) {
    for (int i = 0; i < 4; i++)
      for (int r = 0; r < 4; r++) {
        size_t m = mw + i * 16 + g * 4 + r;
        int bb = (int)(m >> 11), pos = (int)(m & 2047);
        size_t base = ((size_t)(bb * NHEAD + head) * SEQ + pos) * HD;
        for (int j = 0; j < 4; j++)
          Vb[base + j * 16 + l15] = f2bf(acc[i][j][r] + bia[j]);
      }
  } else {
    unsigned short* dst = sec ? Kb : Qb;
    for (int i = 0; i < 4; i++)
      for (int r = 0; r < 4; r++) {
        size_t m = mw + i * 16 + g * 4 + r;
        int bb = (int)(m >> 11), pos = (int)(m & 2047);
        size_t base = ((size_t)(bb * NHEAD + head) * SEQ + pos) * HD;
        const float* cr = cosT + pos * 32;
        const float* sr = sinT + pos * 32;
        for (int pl = 0; pl < 2; pl++) {
          int ii = pl * 16 + l15;           // 0..31
          float c = cr[ii], s = sr[ii];
          float lo = acc[i][pl][r] + bia[pl];
          float hi = acc[i][pl + 2][r] + bia[pl + 2];
          dst[base + ii]      = f2bf(c * lo - s * hi);
          dst[base + 32 + ii] = f2bf(s * lo + c * hi);
        }
      }
  }
}

// ---------------- out-projection GEMM + bias -> fp32 ----------------
__global__ __launch_bounds__(256) void k_out_gemm(const unsigned short* __restrict__ A,
                                                  const unsigned short* __restrict__ Bt,
                                                  const float* __restrict__ bias,
                                                  float* __restrict__ out) {
  __shared__ alignas(16) unsigned short Al[128 * 72];
  __shared__ alignas(16) unsigned short Bl[128 * 72];
  const int tid = threadIdx.x;
  const int lane = tid & 63, l15 = lane & 15, g = lane >> 4;
  const int wid = tid >> 6, wm = wid >> 1, wn = wid & 1;
  const size_t m0 = (size_t)blockIdx.y * 128;
  const size_t n0 = (size_t)blockIdx.x * 128;
  f32x4 acc[4][4] = {};
  gemm_mainloop(A, Bt, Al, Bl, m0, n0, tid, l15, g, wm, wn, acc);

  const int cbase = (int)n0 + wn * 64;
  const size_t mw = m0 + wm * 64;
  for (int i = 0; i < 4; i++)
    for (int r = 0; r < 4; r++) {
      size_t m = mw + i * 16 + g * 4 + r;
      for (int j = 0; j < 4; j++) {
        int col = cbase + j * 16 + l15;
        out[m * EMBED + col] = acc[i][j][r] + bias[col];
      }
    }
}

// ---------------- flash attention ----------------
// block: 4 waves, one (b,h), 64 q-rows (16 per wave). K-tiles of 64 keys.
__global__ __launch_bounds__(256) void k_attn(const unsigned short* __restrict__ Q,
                                              const unsigned short* __restrict__ Kg,
                                              const unsigned short* __restrict__ V,
                                              unsigned short* __restrict__ AO) {
  __shared__ alignas(16) unsigned short Kt[64 * 72];
  __shared__ alignas(16) unsigned short Vt[64 * 72];   // transposed: [hd][key]
  __shared__ alignas(16) unsigned short Pl[4][16 * 72];
  const int tid = threadIdx.x, w = tid >> 6, lane = tid & 63, l15 = lane & 15, g = lane >> 4;
  const int bh = blockIdx.y;
  const size_t hoff = (size_t)bh * SEQ * HD;
  const unsigned short* Qp = Q + hoff;
  const unsigned short* Kp = Kg + hoff;
  const unsigned short* Vp = V + hoff;
  const int q0 = blockIdx.x * 64 + w * 16;

  short8 aq[2];
  for (int kk = 0; kk < 2; kk++)
    aq[kk] = *reinterpret_cast<const short8*>(Qp + (size_t)(q0 + l15) * HD + kk * 32 + g * 8);

  f32x4 o[4] = {};
  float mrow[4] = {-INFINITY, -INFINITY, -INFINITY, -INFINITY};
  float lrow[4] = {0.f, 0.f, 0.f, 0.f};

  for (int t = 0; t < SEQ / 64; t++) {
    __syncthreads();
    int kb = t * 64;
    for (int it = 0; it < 2; it++) {
      int idx = it * 256 + tid;
      int row = idx >> 3, ch = idx & 7;
      uint4 kv = *reinterpret_cast<const uint4*>(Kp + (size_t)(kb + row) * HD + ch * 8);
      *reinterpret_cast<uint4*>(Kt + row * 72 + ch * 8) = kv;
      uint4 vv = *reinterpret_cast<const uint4*>(Vp + (size_t)(kb + row) * HD + ch * 8);
      int c8 = ch * 8;
      Vt[(c8 + 0) * 72 + row] = (unsigned short)(vv.x & 0xffff);
      Vt[(c8 + 1) * 72 + row] = (unsigned short)(vv.x >> 16);
      Vt[(c8 + 2) * 72 + row] = (unsigned short)(vv.y & 0xffff);
      Vt[(c8 + 3) * 72 + row] = (unsigned short)(vv.y >> 16);
      Vt[(c8 + 4) * 72 + row] = (unsigned short)(vv.z & 0xffff);
      Vt[(c8 + 5) * 72 + row] = (unsigned short)(vv.z >> 16);
      Vt[(c8 + 6) * 72 + row] = (unsigned short)(vv.w & 0xffff);
      Vt[(c8 + 7) * 72 + row] = (unsigned short)(vv.w >> 16);
    }
    __syncthreads();

    // S = Q * K^T  (rows q: g*4+r, cols key: c*16+l15)
    f32x4 s[4] = {};
    for (int kk = 0; kk < 2; kk++)
      for (int c = 0; c < 4; c++) {
        short8 bk = *reinterpret_cast<const short8*>(Kt + (c * 16 + l15) * 72 + kk * 32 + g * 8);
        s[c] = __builtin_amdgcn_mfma_f32_16x16x32_bf16(aq[kk], bk, s[c], 0, 0, 0);
      }
    for (int c = 0; c < 4; c++)
      for (int r = 0; r < 4; r++) s[c][r] *= 0.125f;

    // online softmax per q-row
    for (int r = 0; r < 4; r++) {
      float tm = fmaxf(fmaxf(s[0][r], s[1][r]), fmaxf(s[2][r], s[3][r]));
      for (int msk = 1; msk < 16; msk <<= 1) tm = fmaxf(tm, __shfl_xor(tm, msk, 64));
      float mn = fmaxf(mrow[r], tm);
      float fac = __expf(mrow[r] - mn);
      mrow[r] = mn;
      float rs = 0.f;
      for (int c = 0; c < 4; c++) {
        float p = __expf(s[c][r] - mn);
        s[c][r] = p;
        rs += p;
      }
      for (int msk = 1; msk < 16; msk <<= 1) rs += __shfl_xor(rs, msk, 64);
      lrow[r] = lrow[r] * fac + rs;
      for (int c2 = 0; c2 < 4; c2++) o[c2][r] *= fac;
      for (int c = 0; c < 4; c++)
        Pl[w][(g * 4 + r) * 72 + c * 16 + l15] = f2bf(s[c][r]);
    }

    // O += P * V   (A = P from LDS, B = V^T tile)
    for (int kk = 0; kk < 2; kk++) {
      short8 ap = *reinterpret_cast<const short8*>(&Pl[w][l15 * 72 + kk * 32 + g * 8]);
      for (int c2 = 0; c2 < 4; c2++) {
        short8 bv = *reinterpret_cast<const short8*>(Vt + (c2 * 16 + l15) * 72 + kk * 32 + g * 8);
        o[c2] = __builtin_amdgcn_mfma_f32_16x16x32_bf16(ap, bv, o[c2], 0, 0, 0);
      }
    }
  }

  const int bb = bh >> 4, h = bh & 15;
  for (int r = 0; r < 4; r++) {
    float inv = 1.f / lrow[r];
    int pos = q0 + g * 4 + r;
    unsigned short* dst = AO + ((size_t)bb * SEQ + pos) * EMBED + h * HD;
    for (int c2 = 0; c2 < 4; c2++)
      dst[c2 * 16 + l15] = f2bf(o[c2][r] * inv);
  }
}

// ---------------- launch ----------------
extern "C" void kernel_launch(void* const* d_in, const int* in_sizes, int n_in,
                              void* d_out, int out_size, void* d_ws, size_t ws_size,
                              hipStream_t stream) {
  const float* x    = (const float*)d_in[0];
  const float* Wqkv = (const float*)d_in[1];
  const float* bqkv = (const float*)d_in[2];
  const float* Wout = (const float*)d_in[3];
  const float* bout = (const float*)d_in[4];
  float* out = (float*)d_out;

  char* ws = (char*)d_ws;
  size_t off = 0;
  auto carve = [&](size_t bytes) {
    char* p = ws + off;
    off += (bytes + 255) & ~(size_t)255;
    return p;
  };
  float* cosT           = (float*)carve((size_t)SEQ * 32 * 4);
  float* sinT           = (float*)carve((size_t)SEQ * 32 * 4);
  unsigned short* Xb    = (unsigned short*)carve((size_t)MTOT * EMBED * 2);
  unsigned short* WqkvT = (unsigned short*)carve((size_t)QKVN * EMBED * 2);
  unsigned short* WoT   = (unsigned short*)carve((size_t)EMBED * EMBED * 2);
  unsigned short* Qb    = (unsigned short*)carve((size_t)MTOT * EMBED * 2);
  unsigned short* Kb    = (unsigned short*)carve((size_t)MTOT * EMBED * 2);
  unsigned short* Vb    = (unsigned short*)carve((size_t)MTOT * EMBED * 2);
  unsigned short* AO    = (unsigned short*)carve((size_t)MTOT * EMBED * 2);

  k_cvt<<<(MTOT * EMBED / 4 + 255) / 256, 256, 0, stream>>>(x, Xb, MTOT * EMBED / 4);
  k_transpose_cvt<<<dim3(QKVN / 32, EMBED / 32), 256, 0, stream>>>(Wqkv, WqkvT, EMBED, QKVN);
  k_transpose_cvt<<<dim3(EMBED / 32, EMBED / 32), 256, 0, stream>>>(Wout, WoT, EMBED, EMBED);
  k_rope_tables<<<(SEQ * 32) / 256, 256, 0, stream>>>(cosT, sinT);

  k_qkv_gemm<<<dim3(QKVN / 128, MTOT / 128), 256, 0, stream>>>(Xb, WqkvT, bqkv, cosT, sinT, Qb, Kb, Vb);
  k_attn<<<dim3(SEQ / 64, BATCH * NHEAD), 256, 0, stream>>>(Qb, Kb, Vb, AO);
  k_out_gemm<<<dim3(EMBED / 128, MTOT / 128), 256, 0, stream>>>(AO, WoT, bout, out);
}

// Round 2
// 194.717 us; speedup vs baseline: 1.2664x; 1.2664x over previous
//
#include <hip/hip_runtime.h>
#include <hip/hip_bf16.h>
#include <math.h>

#define EMBED 1024
#define NHEAD 16
#define HD 64
#define BATCH 2
#define SEQ 2048
#define MTOT (BATCH * SEQ)   // 4096
#define QKVN (3 * EMBED)     // 3072

typedef __attribute__((ext_vector_type(8))) short short8;
typedef __attribute__((ext_vector_type(4))) float f32x4;

typedef __attribute__((address_space(1))) const unsigned int GUI;
typedef __attribute__((address_space(3))) unsigned int LUI;

__device__ __forceinline__ void gload_lds16(const void* src, void* dst) {
  __builtin_amdgcn_global_load_lds((GUI*)src, (LUI*)dst, 16, 0, 0);
}

__device__ __forceinline__ unsigned short f2bf(float f) {
  unsigned u = __builtin_bit_cast(unsigned, f);
  u += 0x7fffu + ((u >> 16) & 1u);   // RNE
  return (unsigned short)(u >> 16);
}

// ---------------- prep kernels ----------------

__global__ __launch_bounds__(256) void k_cvt(const float* __restrict__ in,
                                             unsigned short* __restrict__ out, int n4) {
  int i = blockIdx.x * 256 + threadIdx.x;
  if (i >= n4) return;
  float4 v = reinterpret_cast<const float4*>(in)[i];
  ushort4 o;
  o.x = f2bf(v.x); o.y = f2bf(v.y); o.z = f2bf(v.z); o.w = f2bf(v.w);
  reinterpret_cast<ushort4*>(out)[i] = o;
}

// W [K][Ncols] f32 -> WT [Ncols][K] bf16
__global__ __launch_bounds__(256) void k_transpose_cvt(const float* __restrict__ W,
                                                       unsigned short* __restrict__ WT,
                                                       int K, int Ncols) {
  __shared__ float tile[32][33];
  int n0 = blockIdx.x * 32, k0 = blockIdx.y * 32;
  int tc = threadIdx.x & 31, tr = threadIdx.x >> 5;
  for (int i = 0; i < 4; i++) {
    int r = tr + i * 8;
    tile[r][tc] = W[(size_t)(k0 + r) * Ncols + n0 + tc];
  }
  __syncthreads();
  for (int i = 0; i < 4; i++) {
    int r = tr + i * 8;
    WT[(size_t)(n0 + r) * K + k0 + tc] = f2bf(tile[tc][r]);
  }
}

__global__ __launch_bounds__(256) void k_rope_tables(float* __restrict__ cosT,
                                                     float* __restrict__ sinT) {
  int idx = blockIdx.x * 256 + threadIdx.x;
  if (idx >= SEQ * 32) return;
  int pos = idx >> 5, i = idx & 31;
  double theta = exp((double)i * -0.28782313662425575);  // ln(10000)/32
  double f = (double)pos * theta;
  cosT[idx] = (float)cos(f);
  sinT[idx] = (float)sin(f);
}

// ---------------- shared GEMM mainloop ----------------
// C tile 128x128, BK=64, 4 waves (2x2), wave tile 64x64 = 4x4 frags of 16x16.
// LDS linear [128][64] shorts; chunk c of row r stored at slot c^(r&7)
// (pre-swizzled global source, global_load_lds 16B, XOR-swizzled reads).
__device__ __forceinline__ void gemm_mainloop(const unsigned short* __restrict__ A,
                                              const unsigned short* __restrict__ Bt,
                                              unsigned short* Al, unsigned short* Bl,
                                              size_t m0, size_t n0,
                                              int tid, int l15, int g, int wm, int wn,
                                              f32x4 acc[4][4]) {
  const int w = tid >> 6;
  const int lane = tid & 63;
  const int srow = lane >> 3, slot = lane & 7;
  for (int k0 = 0; k0 < 1024; k0 += 64) {
    __syncthreads();
    for (int it = 0; it < 4; it++) {
      const int r = w * 32 + it * 8 + srow;
      const int sc = (slot ^ (r & 7)) * 8;
      gload_lds16(A + (m0 + r) * 1024 + k0 + sc, &Al[(w * 32 + it * 8) * 64]);
      gload_lds16(Bt + (n0 + r) * 1024 + k0 + sc, &Bl[(w * 32 + it * 8) * 64]);
    }
    __syncthreads();
    for (int kk = 0; kk < 2; kk++) {
      short8 fa[4], fb[4];
      const int xr = ((kk * 4 + g) ^ (l15 & 7)) * 8;
      for (int i = 0; i < 4; i++)
        fa[i] = *reinterpret_cast<const short8*>(&Al[(wm * 64 + i * 16 + l15) * 64 + xr]);
      for (int j = 0; j < 4; j++)
        fb[j] = *reinterpret_cast<const short8*>(&Bl[(wn * 64 + j * 16 + l15) * 64 + xr]);
      for (int i = 0; i < 4; i++)
        for (int j = 0; j < 4; j++)
          acc[i][j] = __builtin_amdgcn_mfma_f32_16x16x32_bf16(fa[i], fb[j], acc[i][j], 0, 0, 0);
    }
  }
}

// ---------------- QKV GEMM + bias + RoPE + scatter ----------------
// Q is pre-scaled by 1/8 (attention scale, exact in bf16).
// V is written TRANSPOSED per head: Vt_global[b,h,d,n].
__global__ __launch_bounds__(256) void k_qkv_gemm(const unsigned short* __restrict__ A,
                                                  const unsigned short* __restrict__ Bt,
                                                  const float* __restrict__ bias,
                                                  const float* __restrict__ cosT,
                                                  const float* __restrict__ sinT,
                                                  unsigned short* __restrict__ Qb,
                                                  unsigned short* __restrict__ Kb,
                                                  unsigned short* __restrict__ Vtg) {
  __shared__ alignas(16) unsigned short Al[128 * 64];
  __shared__ alignas(16) unsigned short Bl[128 * 64];
  const int tid = threadIdx.x;
  const int lane = tid & 63, l15 = lane & 15, g = lane >> 4;
  const int wid = tid >> 6, wm = wid >> 1, wn = wid & 1;
  const size_t m0 = (size_t)blockIdx.y * 128;
  const size_t n0 = (size_t)blockIdx.x * 128;
  f32x4 acc[4][4] = {};
  gemm_mainloop(A, Bt, Al, Bl, m0, n0, tid, l15, g, wm, wn, acc);

  const int cbase = (int)n0 + wn * 64;       // wave spans exactly one head (64 cols)
  const int sec = cbase >> 10;               // 0=Q 1=K 2=V
  const int head = (cbase & 1023) >> 6;
  float bia[4];
  for (int j = 0; j < 4; j++) bia[j] = bias[cbase + j * 16 + l15];
  const size_t mw = m0 + wm * 64;

  if (sec == 2) {
    for (int i = 0; i < 4; i++)
      for (int r = 0; r < 4; r++) {
        size_t m = mw + i * 16 + g * 4 + r;
        int bb = (int)(m >> 11), pos = (int)(m & 2047);
        size_t hb = (size_t)(bb * NHEAD + head) * HD;
        for (int j = 0; j < 4; j++) {
          int d = j * 16 + l15;
          Vtg[(hb + d) * SEQ + pos] = f2bf(acc[i][j][r] + bia[j]);
        }
      }
  } else {
    unsigned short* dst = sec ? Kb : Qb;
    const float qs = sec ? 1.0f : 0.125f;
    for (int i = 0; i < 4; i++)
      for (int r = 0; r < 4; r++) {
        size_t m = mw + i * 16 + g * 4 + r;
        int bb = (int)(m >> 11), pos = (int)(m & 2047);
        size_t base = ((size_t)(bb * NHEAD + head) * SEQ + pos) * HD;
        const float* cr = cosT + pos * 32;
        const float* sr = sinT + pos * 32;
        for (int pl = 0; pl < 2; pl++) {
          int ii = pl * 16 + l15;           // 0..31
          float c = cr[ii], s = sr[ii];
          float lo = acc[i][pl][r] + bia[pl];
          float hi = acc[i][pl + 2][r] + bia[pl + 2];
          dst[base + ii]      = f2bf((c * lo - s * hi) * qs);
          dst[base + 32 + ii] = f2bf((s * lo + c * hi) * qs);
        }
      }
  }
}

// ---------------- out-projection GEMM + bias -> fp32 ----------------
__global__ __launch_bounds__(256) void k_out_gemm(const unsigned short* __restrict__ A,
                                                  const unsigned short* __restrict__ Bt,
                                                  const float* __restrict__ bias,
                                                  float* __restrict__ out) {
  __shared__ alignas(16) unsigned short Al[128 * 64];
  __shared__ alignas(16) unsigned short Bl[128 * 64];
  const int tid = threadIdx.x;
  const int lane = tid & 63, l15 = lane & 15, g = lane >> 4;
  const int wid = tid >> 6, wm = wid >> 1, wn = wid & 1;
  const size_t m0 = (size_t)blockIdx.y * 128;
  const size_t n0 = (size_t)blockIdx.x * 128;
  f32x4 acc[4][4] = {};
  gemm_mainloop(A, Bt, Al, Bl, m0, n0, tid, l15, g, wm, wn, acc);

  const int cbase = (int)n0 + wn * 64;
  const size_t mw = m0 + wm * 64;
  for (int i = 0; i < 4; i++)
    for (int r = 0; r < 4; r++) {
      size_t m = mw + i * 16 + g * 4 + r;
      for (int j = 0; j < 4; j++) {
        int col = cbase + j * 16 + l15;
        out[m * EMBED + col] = acc[i][j][r] + bias[col];
      }
    }
}

// ---------------- flash attention ----------------
// block: 4 waves, one (b,h), 64 q-rows (16 per wave). K-tiles of 64 keys.
// K [bh][n][d] and V^T [bh][d][n] staged via global_load_lds with XOR-chunk
// swizzle (LDS linear [64][64], chunk c of row r at slot c^(r&7)).
__global__ __launch_bounds__(256) void k_attn(const unsigned short* __restrict__ Q,
                                              const unsigned short* __restrict__ Kg,
                                              const unsigned short* __restrict__ Vtg,
                                              unsigned short* __restrict__ AO) {
  __shared__ alignas(16) unsigned short Kt[64 * 64];
  __shared__ alignas(16) unsigned short Vt[64 * 64];   // V^T tile: [d][k]
  __shared__ alignas(16) unsigned short Pl[4][16 * 64];
  const int tid = threadIdx.x, w = tid >> 6, lane = tid & 63;
  const int l15 = lane & 15, g = lane >> 4;
  const int srow = lane >> 3, slot = lane & 7;
  const int bh = blockIdx.y;
  const unsigned short* Qp = Q + (size_t)bh * SEQ * HD;
  const unsigned short* Kp = Kg + (size_t)bh * SEQ * HD;
  const unsigned short* Vp = Vtg + (size_t)bh * HD * SEQ;
  const int q0 = blockIdx.x * 64 + w * 16;

  short8 aq[2];
  for (int kk = 0; kk < 2; kk++)
    aq[kk] = *reinterpret_cast<const short8*>(Qp + (size_t)(q0 + l15) * HD + kk * 32 + g * 8);

  f32x4 o[4] = {};
  float mrow[4] = {-INFINITY, -INFINITY, -INFINITY, -INFINITY};
  float lrow[4] = {0.f, 0.f, 0.f, 0.f};

  for (int t = 0; t < SEQ / 64; t++) {
    const int kb = t * 64;
    __syncthreads();
    for (int it = 0; it < 2; it++) {
      const int r = w * 16 + it * 8 + srow;     // 0..63: K key-row / V d-row
      const int sc = (slot ^ (r & 7)) * 8;
      gload_lds16(Kp + (size_t)(kb + r) * HD + sc, &Kt[(w * 16 + it * 8) * 64]);
      gload_lds16(Vp + (size_t)r * SEQ + kb + sc, &Vt[(w * 16 + it * 8) * 64]);
    }
    __syncthreads();

    // S = Q * K^T  (rows q: g*4+r, cols key: c*16+l15); Q pre-scaled by 1/8
    f32x4 s[4] = {};
    for (int kk = 0; kk < 2; kk++) {
      const int xr = ((kk * 4 + g) ^ (l15 & 7)) * 8;
      for (int c = 0; c < 4; c++) {
        short8 bk = *reinterpret_cast<const short8*>(&Kt[(c * 16 + l15) * 64 + xr]);
        s[c] = __builtin_amdgcn_mfma_f32_16x16x32_bf16(aq[kk], bk, s[c], 0, 0, 0);
      }
    }

    // online softmax per q-row
    for (int r = 0; r < 4; r++) {
      float tm = fmaxf(fmaxf(s[0][r], s[1][r]), fmaxf(s[2][r], s[3][r]));
      for (int msk = 1; msk < 16; msk <<= 1) tm = fmaxf(tm, __shfl_xor(tm, msk, 64));
      float mn = fmaxf(mrow[r], tm);
      float fac = __expf(mrow[r] - mn);
      mrow[r] = mn;
      float rs = 0.f;
      const int qrow = g * 4 + r;
      for (int c = 0; c < 4; c++) {
        float p = __expf(s[c][r] - mn);
        rs += p;
        Pl[w][qrow * 64 + (((2 * c + (l15 >> 3)) ^ (qrow & 7)) * 8) + (l15 & 7)] = f2bf(p);
      }
      for (int msk = 1; msk < 16; msk <<= 1) rs += __shfl_xor(rs, msk, 64);
      lrow[r] = lrow[r] * fac + rs;
      for (int c2 = 0; c2 < 4; c2++) o[c2][r] *= fac;
    }

    // O += P * V   (A = P from LDS, B = V^T tile)
    for (int kk = 0; kk < 2; kk++) {
      const int xr = ((kk * 4 + g) ^ (l15 & 7)) * 8;
      short8 ap = *reinterpret_cast<const short8*>(&Pl[w][l15 * 64 + xr]);
      for (int c2 = 0; c2 < 4; c2++) {
        short8 bv = *reinterpret_cast<const short8*>(&Vt[(c2 * 16 + l15) * 64 + xr]);
        o[c2] = __builtin_amdgcn_mfma_f32_16x16x32_bf16(ap, bv, o[c2], 0, 0, 0);
      }
    }
  }

  const int bb = bh >> 4, h = bh & 15;
  for (int r = 0; r < 4; r++) {
    float inv = 1.f / lrow[r];
    int pos = q0 + g * 4 + r;
    unsigned short* dst = AO + ((size_t)bb * SEQ + pos) * EMBED + h * HD;
    for (int c2 = 0; c2 < 4; c2++)
      dst[c2 * 16 + l15] = f2bf(o[c2][r] * inv);
  }
}

// ---------------- launch ----------------
extern "C" void kernel_launch(void* const* d_in, const int* in_sizes, int n_in,
                              void* d_out, int out_size, void* d_ws, size_t ws_size,
                              hipStream_t stream) {
  const float* x    = (const float*)d_in[0];
  const float* Wqkv = (const float*)d_in[1];
  const float* bqkv = (const float*)d_in[2];
  const float* Wout = (const float*)d_in[3];
  const float* bout = (const float*)d_in[4];
  float* out = (float*)d_out;

  char* ws = (char*)d_ws;
  size_t off = 0;
  auto carve = [&](size_t bytes) {
    char* p = ws + off;
    off += (bytes + 255) & ~(size_t)255;
    return p;
  };
  float* cosT           = (float*)carve((size_t)SEQ * 32 * 4);
  float* sinT           = (float*)carve((size_t)SEQ * 32 * 4);
  unsigned short* Xb    = (unsigned short*)carve((size_t)MTOT * EMBED * 2);
  unsigned short* WqkvT = (unsigned short*)carve((size_t)QKVN * EMBED * 2);
  unsigned short* WoT   = (unsigned short*)carve((size_t)EMBED * EMBED * 2);
  unsigned short* Qb    = (unsigned short*)carve((size_t)MTOT * EMBED * 2);
  unsigned short* Kb    = (unsigned short*)carve((size_t)MTOT * EMBED * 2);
  unsigned short* Vtg   = (unsigned short*)carve((size_t)MTOT * EMBED * 2);
  unsigned short* AO    = (unsigned short*)carve((size_t)MTOT * EMBED * 2);

  k_cvt<<<(MTOT * EMBED / 4 + 255) / 256, 256, 0, stream>>>(x, Xb, MTOT * EMBED / 4);
  k_transpose_cvt<<<dim3(QKVN / 32, EMBED / 32), 256, 0, stream>>>(Wqkv, WqkvT, EMBED, QKVN);
  k_transpose_cvt<<<dim3(EMBED / 32, EMBED / 32), 256, 0, stream>>>(Wout, WoT, EMBED, EMBED);
  k_rope_tables<<<(SEQ * 32) / 256, 256, 0, stream>>>(cosT, sinT);

  k_qkv_gemm<<<dim3(QKVN / 128, MTOT / 128), 256, 0, stream>>>(Xb, WqkvT, bqkv, cosT, sinT, Qb, Kb, Vtg);
  k_attn<<<dim3(SEQ / 64, BATCH * NHEAD), 256, 0, stream>>>(Qb, Kb, Vtg, AO);
  k_out_gemm<<<dim3(EMBED / 128, MTOT / 128), 256, 0, stream>>>(AO, WoT, bout, out);
}

// Round 3
// 153.776 us; speedup vs baseline: 1.6036x; 1.2662x over previous
//
#include <hip/hip_runtime.h>
#include <hip/hip_bf16.h>
#include <math.h>

#define EMBED 1024
#define NHEAD 16
#define HD 64
#define BATCH 2
#define SEQ 2048
#define MTOT (BATCH * SEQ)   // 4096
#define QKVN (3 * EMBED)     // 3072

typedef __attribute__((ext_vector_type(8))) short short8;
typedef __attribute__((ext_vector_type(4))) float f32x4;

typedef __attribute__((address_space(1))) const unsigned int GUI;
typedef __attribute__((address_space(3))) unsigned int LUI;

__device__ __forceinline__ void gload_lds16(const void* src, void* dst) {
  __builtin_amdgcn_global_load_lds((GUI*)src, (LUI*)dst, 16, 0, 0);
}

__device__ __forceinline__ unsigned short f2bf(float f) {
  unsigned u = __builtin_bit_cast(unsigned, f);
  u += 0x7fffu + ((u >> 16) & 1u);   // RNE
  return (unsigned short)(u >> 16);
}

__device__ __forceinline__ unsigned cvt_pk_bf16(float lo, float hi) {
  unsigned r;
  asm("v_cvt_pk_bf16_f32 %0, %1, %2" : "=v"(r) : "v"(lo), "v"(hi));
  return r;
}

// ---------------- prep kernels ----------------

__global__ __launch_bounds__(256) void k_cvt(const float* __restrict__ in,
                                             unsigned short* __restrict__ out, int n4) {
  int i = blockIdx.x * 256 + threadIdx.x;
  if (i >= n4) return;
  float4 v = reinterpret_cast<const float4*>(in)[i];
  ushort4 o;
  o.x = f2bf(v.x); o.y = f2bf(v.y); o.z = f2bf(v.z); o.w = f2bf(v.w);
  reinterpret_cast<ushort4*>(out)[i] = o;
}

// W [K][Ncols] f32 -> WT [Ncols][K] bf16
__global__ __launch_bounds__(256) void k_transpose_cvt(const float* __restrict__ W,
                                                       unsigned short* __restrict__ WT,
                                                       int K, int Ncols) {
  __shared__ float tile[32][33];
  int n0 = blockIdx.x * 32, k0 = blockIdx.y * 32;
  int tc = threadIdx.x & 31, tr = threadIdx.x >> 5;
  for (int i = 0; i < 4; i++) {
    int r = tr + i * 8;
    tile[r][tc] = W[(size_t)(k0 + r) * Ncols + n0 + tc];
  }
  __syncthreads();
  for (int i = 0; i < 4; i++) {
    int r = tr + i * 8;
    WT[(size_t)(n0 + r) * K + k0 + tc] = f2bf(tile[tc][r]);
  }
}

__global__ __launch_bounds__(256) void k_rope_tables(float* __restrict__ cosT,
                                                     float* __restrict__ sinT) {
  int idx = blockIdx.x * 256 + threadIdx.x;
  if (idx >= SEQ * 32) return;
  int pos = idx >> 5, i = idx & 31;
  double theta = exp((double)i * -0.28782313662425575);  // ln(10000)/32
  double f = (double)pos * theta;
  cosT[idx] = (float)cos(f);
  sinT[idx] = (float)sin(f);
}

// ---------------- shared GEMM mainloop ----------------
// C tile 128x128, BK=64, 4 waves (2x2), wave tile 64x64 = 4x4 frags of 16x16.
// LDS linear [128][64] shorts; chunk c of row r stored at slot c^(r&7)
// (pre-swizzled global source, global_load_lds 16B, XOR-swizzled reads).
__device__ __forceinline__ void gemm_mainloop(const unsigned short* __restrict__ A,
                                              const unsigned short* __restrict__ Bt,
                                              unsigned short* Al, unsigned short* Bl,
                                              size_t m0, size_t n0,
                                              int tid, int l15, int g, int wm, int wn,
                                              f32x4 acc[4][4]) {
  const int w = tid >> 6;
  const int lane = tid & 63;
  const int srow = lane >> 3, slot = lane & 7;
  for (int k0 = 0; k0 < 1024; k0 += 64) {
    __syncthreads();
    for (int it = 0; it < 4; it++) {
      const int r = w * 32 + it * 8 + srow;
      const int sc = (slot ^ (r & 7)) * 8;
      gload_lds16(A + (m0 + r) * 1024 + k0 + sc, &Al[(w * 32 + it * 8) * 64]);
      gload_lds16(Bt + (n0 + r) * 1024 + k0 + sc, &Bl[(w * 32 + it * 8) * 64]);
    }
    __syncthreads();
    for (int kk = 0; kk < 2; kk++) {
      short8 fa[4], fb[4];
      const int xr = ((kk * 4 + g) ^ (l15 & 7)) * 8;
      for (int i = 0; i < 4; i++)
        fa[i] = *reinterpret_cast<const short8*>(&Al[(wm * 64 + i * 16 + l15) * 64 + xr]);
      for (int j = 0; j < 4; j++)
        fb[j] = *reinterpret_cast<const short8*>(&Bl[(wn * 64 + j * 16 + l15) * 64 + xr]);
      for (int i = 0; i < 4; i++)
        for (int j = 0; j < 4; j++)
          acc[i][j] = __builtin_amdgcn_mfma_f32_16x16x32_bf16(fa[i], fb[j], acc[i][j], 0, 0, 0);
    }
  }
}

// ---------------- QKV GEMM + bias + RoPE + scatter ----------------
// Q is pre-scaled by 1/8 (attention scale, exact in bf16).
// V is written TRANSPOSED per head: Vt_global[b,h,d,n].
__global__ __launch_bounds__(256) void k_qkv_gemm(const unsigned short* __restrict__ A,
                                                  const unsigned short* __restrict__ Bt,
                                                  const float* __restrict__ bias,
                                                  const float* __restrict__ cosT,
                                                  const float* __restrict__ sinT,
                                                  unsigned short* __restrict__ Qb,
                                                  unsigned short* __restrict__ Kb,
                                                  unsigned short* __restrict__ Vtg) {
  __shared__ alignas(16) unsigned short Al[128 * 64];
  __shared__ alignas(16) unsigned short Bl[128 * 64];
  const int tid = threadIdx.x;
  const int lane = tid & 63, l15 = lane & 15, g = lane >> 4;
  const int wid = tid >> 6, wm = wid >> 1, wn = wid & 1;
  const size_t m0 = (size_t)blockIdx.y * 128;
  const size_t n0 = (size_t)blockIdx.x * 128;
  f32x4 acc[4][4] = {};
  gemm_mainloop(A, Bt, Al, Bl, m0, n0, tid, l15, g, wm, wn, acc);

  const int cbase = (int)n0 + wn * 64;       // wave spans exactly one head (64 cols)
  const int sec = cbase >> 10;               // 0=Q 1=K 2=V
  const int head = (cbase & 1023) >> 6;
  float bia[4];
  for (int j = 0; j < 4; j++) bia[j] = bias[cbase + j * 16 + l15];
  const size_t mw = m0 + wm * 64;

  if (sec == 2) {
    for (int i = 0; i < 4; i++)
      for (int r = 0; r < 4; r++) {
        size_t m = mw + i * 16 + g * 4 + r;
        int bb = (int)(m >> 11), pos = (int)(m & 2047);
        size_t hb = (size_t)(bb * NHEAD + head) * HD;
        for (int j = 0; j < 4; j++) {
          int d = j * 16 + l15;
          Vtg[(hb + d) * SEQ + pos] = f2bf(acc[i][j][r] + bia[j]);
        }
      }
  } else {
    unsigned short* dst = sec ? Kb : Qb;
    const float qs = sec ? 1.0f : 0.125f;
    for (int i = 0; i < 4; i++)
      for (int r = 0; r < 4; r++) {
        size_t m = mw + i * 16 + g * 4 + r;
        int bb = (int)(m >> 11), pos = (int)(m & 2047);
        size_t base = ((size_t)(bb * NHEAD + head) * SEQ + pos) * HD;
        const float* cr = cosT + pos * 32;
        const float* sr = sinT + pos * 32;
        for (int pl = 0; pl < 2; pl++) {
          int ii = pl * 16 + l15;           // 0..31
          float c = cr[ii], s = sr[ii];
          float lo = acc[i][pl][r] + bia[pl];
          float hi = acc[i][pl + 2][r] + bia[pl + 2];
          dst[base + ii]      = f2bf((c * lo - s * hi) * qs);
          dst[base + 32 + ii] = f2bf((s * lo + c * hi) * qs);
        }
      }
  }
}

// ---------------- out-projection GEMM + bias -> fp32 ----------------
__global__ __launch_bounds__(256) void k_out_gemm(const unsigned short* __restrict__ A,
                                                  const unsigned short* __restrict__ Bt,
                                                  const float* __restrict__ bias,
                                                  float* __restrict__ out) {
  __shared__ alignas(16) unsigned short Al[128 * 64];
  __shared__ alignas(16) unsigned short Bl[128 * 64];
  const int tid = threadIdx.x;
  const int lane = tid & 63, l15 = lane & 15, g = lane >> 4;
  const int wid = tid >> 6, wm = wid >> 1, wn = wid & 1;
  const size_t m0 = (size_t)blockIdx.y * 128;
  const size_t n0 = (size_t)blockIdx.x * 128;
  f32x4 acc[4][4] = {};
  gemm_mainloop(A, Bt, Al, Bl, m0, n0, tid, l15, g, wm, wn, acc);

  const int cbase = (int)n0 + wn * 64;
  const size_t mw = m0 + wm * 64;
  for (int i = 0; i < 4; i++)
    for (int r = 0; r < 4; r++) {
      size_t m = mw + i * 16 + g * 4 + r;
      for (int j = 0; j < 4; j++) {
        int col = cbase + j * 16 + l15;
        out[m * EMBED + col] = acc[i][j][r] + bias[col];
      }
    }
}

// ---------------- flash attention (swapped-operand, in-register softmax) ---
// block: 4 waves, one (b,h), 64 q-rows (16 per wave). K-tiles of 64 keys.
// S^T = mfma(K, Q): lane holds S[key=c*16+g*4+r][q=l15] -> full P-row per q
// lives in ONE lane. PV uses a k-permutation so the B-frag is lane-local.
__global__ __launch_bounds__(256) void k_attn(const unsigned short* __restrict__ Q,
                                              const unsigned short* __restrict__ Kg,
                                              const unsigned short* __restrict__ Vtg,
                                              unsigned short* __restrict__ AO) {
  __shared__ alignas(16) unsigned short Kt[64 * 64];
  __shared__ alignas(16) unsigned short Vt[64 * 64];   // V^T tile: [d][k]
  const int tid = threadIdx.x, w = tid >> 6, lane = tid & 63;
  const int l15 = lane & 15, g = lane >> 4;
  const int srow = lane >> 3, slot = lane & 7;
  const int bh = blockIdx.y;
  const unsigned short* Qp = Q + (size_t)bh * SEQ * HD;
  const unsigned short* Kp = Kg + (size_t)bh * SEQ * HD;
  const unsigned short* Vp = Vtg + (size_t)bh * HD * SEQ;
  const int q0 = blockIdx.x * 64 + w * 16;

  short8 aq[2];
  for (int kk = 0; kk < 2; kk++)
    aq[kk] = *reinterpret_cast<const short8*>(Qp + (size_t)(q0 + l15) * HD + kk * 32 + g * 8);

  f32x4 o[4] = {};                 // O^T[d=c2*16+g*4+r][q=l15]
  float mrow = -INFINITY, lrow = 0.f;

  for (int t = 0; t < SEQ / 64; t++) {
    const int kb = t * 64;
    __syncthreads();
    for (int it = 0; it < 2; it++) {
      const int r = w * 16 + it * 8 + srow;     // 0..63: K key-row / V d-row
      const int sc = (slot ^ (r & 7)) * 8;
      gload_lds16(Kp + (size_t)(kb + r) * HD + sc, &Kt[(w * 16 + it * 8) * 64]);
      gload_lds16(Vp + (size_t)r * SEQ + kb + sc, &Vt[(w * 16 + it * 8) * 64]);
    }
    __syncthreads();

    // S^T = K * Q^T: s[c][r] = S[key=c*16+g*4+r][q=l15]  (Q pre-scaled 1/8)
    f32x4 s[4] = {};
    for (int kk = 0; kk < 2; kk++) {
      const int xr = ((kk * 4 + g) ^ (l15 & 7)) * 8;
      for (int c = 0; c < 4; c++) {
        short8 ak = *reinterpret_cast<const short8*>(&Kt[(c * 16 + l15) * 64 + xr]);
        s[c] = __builtin_amdgcn_mfma_f32_16x16x32_bf16(ak, aq[kk], s[c], 0, 0, 0);
      }
    }

    // in-register online softmax (per lane = per q-row)
    float tm = s[0][0];
#pragma unroll
    for (int c = 0; c < 4; c++)
#pragma unroll
      for (int r = 0; r < 4; r++) tm = fmaxf(tm, s[c][r]);
    tm = fmaxf(tm, __shfl_xor(tm, 16, 64));
    tm = fmaxf(tm, __shfl_xor(tm, 32, 64));

    if (!__all(tm <= mrow + 8.0f)) {           // defer-max (T13, THR=8)
      float mn = fmaxf(mrow, tm);
      float fac = __expf(mrow - mn);
      lrow *= fac;
#pragma unroll
      for (int c2 = 0; c2 < 4; c2++)
#pragma unroll
        for (int r = 0; r < 4; r++) o[c2][r] *= fac;
      mrow = mn;
    }

    float rs = 0.f;
    unsigned wpk[8];                           // packed P: wpk[2c+u] = keys (16c+4g+2u, +1)
#pragma unroll
    for (int c = 0; c < 4; c++) {
      float p0 = __expf(s[c][0] - mrow);
      float p1 = __expf(s[c][1] - mrow);
      float p2 = __expf(s[c][2] - mrow);
      float p3 = __expf(s[c][3] - mrow);
      rs += (p0 + p1) + (p2 + p3);
      wpk[2 * c]     = cvt_pk_bf16(p0, p1);
      wpk[2 * c + 1] = cvt_pk_bf16(p2, p3);
    }
    rs += __shfl_xor(rs, 16, 64);
    rs += __shfl_xor(rs, 32, 64);
    lrow += rs;

    // O^T += V^T * P  with k-permutation: slot(g,j) <-> key (2kk+(j>>2))*16+g*4+(j&3)
#pragma unroll
    for (int kk = 0; kk < 2; kk++) {
      short8 pb = __builtin_bit_cast(short8,
          uint4{wpk[4 * kk], wpk[4 * kk + 1], wpk[4 * kk + 2], wpk[4 * kk + 3]});
#pragma unroll
      for (int c2 = 0; c2 < 4; c2++) {
        const unsigned short* vrow = &Vt[(c2 * 16 + l15) * 64];
        const int rx = l15 & 7;
        uint2 v1 = *reinterpret_cast<const uint2*>(vrow + ((4 * kk + (g >> 1)) ^ rx) * 8 + (g & 1) * 4);
        uint2 v2 = *reinterpret_cast<const uint2*>(vrow + ((4 * kk + 2 + (g >> 1)) ^ rx) * 8 + (g & 1) * 4);
        short8 av = __builtin_bit_cast(short8, uint4{v1.x, v1.y, v2.x, v2.y});
        o[c2] = __builtin_amdgcn_mfma_f32_16x16x32_bf16(av, pb, o[c2], 0, 0, 0);
      }
    }
  }

  const int bb = bh >> 4, h = bh & 15;
  const float inv = 1.f / lrow;
  const int pos = q0 + l15;
  unsigned short* dst = AO + ((size_t)bb * SEQ + pos) * EMBED + h * HD;
#pragma unroll
  for (int c2 = 0; c2 < 4; c2++) {
    uint2 pk;
    pk.x = cvt_pk_bf16(o[c2][0] * inv, o[c2][1] * inv);
    pk.y = cvt_pk_bf16(o[c2][2] * inv, o[c2][3] * inv);
    *reinterpret_cast<uint2*>(dst + c2 * 16 + g * 4) = pk;
  }
}

// ---------------- launch ----------------
extern "C" void kernel_launch(void* const* d_in, const int* in_sizes, int n_in,
                              void* d_out, int out_size, void* d_ws, size_t ws_size,
                              hipStream_t stream) {
  const float* x    = (const float*)d_in[0];
  const float* Wqkv = (const float*)d_in[1];
  const float* bqkv = (const float*)d_in[2];
  const float* Wout = (const float*)d_in[3];
  const float* bout = (const float*)d_in[4];
  float* out = (float*)d_out;

  char* ws = (char*)d_ws;
  size_t off = 0;
  auto carve = [&](size_t bytes) {
    char* p = ws + off;
    off += (bytes + 255) & ~(size_t)255;
    return p;
  };
  float* cosT           = (float*)carve((size_t)SEQ * 32 * 4);
  float* sinT           = (float*)carve((size_t)SEQ * 32 * 4);
  unsigned short* Xb    = (unsigned short*)carve((size_t)MTOT * EMBED * 2);
  unsigned short* WqkvT = (unsigned short*)carve((size_t)QKVN * EMBED * 2);
  unsigned short* WoT   = (unsigned short*)carve((size_t)EMBED * EMBED * 2);
  unsigned short* Qb    = (unsigned short*)carve((size_t)MTOT * EMBED * 2);
  unsigned short* Kb    = (unsigned short*)carve((size_t)MTOT * EMBED * 2);
  unsigned short* Vtg   = (unsigned short*)carve((size_t)MTOT * EMBED * 2);
  unsigned short* AO    = (unsigned short*)carve((size_t)MTOT * EMBED * 2);

  k_cvt<<<(MTOT * EMBED / 4 + 255) / 256, 256, 0, stream>>>(x, Xb, MTOT * EMBED / 4);
  k_transpose_cvt<<<dim3(QKVN / 32, EMBED / 32), 256, 0, stream>>>(Wqkv, WqkvT, EMBED, QKVN);
  k_transpose_cvt<<<dim3(EMBED / 32, EMBED / 32), 256, 0, stream>>>(Wout, WoT, EMBED, EMBED);
  k_rope_tables<<<(SEQ * 32) / 256, 256, 0, stream>>>(cosT, sinT);

  k_qkv_gemm<<<dim3(QKVN / 128, MTOT / 128), 256, 0, stream>>>(Xb, WqkvT, bqkv, cosT, sinT, Qb, Kb, Vtg);
  k_attn<<<dim3(SEQ / 64, BATCH * NHEAD), 256, 0, stream>>>(Qb, Kb, Vtg, AO);
  k_out_gemm<<<dim3(EMBED / 128, MTOT / 128), 256, 0, stream>>>(AO, WoT, bout, out);
}